// Round 6
// baseline (554.892 us; speedup 1.0000x reference)
//
#include <hip/hip_runtime.h>
#include <hip/hip_cooperative_groups.h>

namespace cg = cooperative_groups;

namespace {

typedef unsigned short ushort_t;
typedef unsigned int uint_t;
typedef __attribute__((ext_vector_type(8))) short bf16x8;
typedef __attribute__((ext_vector_type(4))) float f32x4;

constexpr int N   = 50000;
constexpr int E   = 600000;
constexpr int NR  = 5;
constexpr int KIN = 768;
constexpr int H   = 128;
constexpr int RD  = 200;

constexpr int NT     = 256;
constexpr int NSCAN  = 196;              // ceil(N/256)
constexpr int GTILES = (N + 63) / 64;    // 782

__device__ inline ushort_t f2b(float f){           // fp32 -> bf16 bits, RNE
  uint_t u = __builtin_bit_cast(uint_t, f);
  uint_t r = (u + 0x7FFFu + ((u >> 16) & 1u)) >> 16;
  return (ushort_t)r;
}
__device__ inline float b2f_lo(uint_t u){ return __builtin_bit_cast(float, u << 16); }
__device__ inline float b2f_hi(uint_t u){ return __builtin_bit_cast(float, u & 0xFFFF0000u); }
__device__ inline float b2f_us(ushort_t h){ return __builtin_bit_cast(float, ((uint_t)h) << 16); }

struct Par {
  const float* x; const int* esrc; const int* edst; const int* et;
  const float* l1W; const float* l1b; const float* l2W; const float* l2b;
  const float* W1;  const float* Wr1; const float* a1; const float* Wres1; const float* rel1;
  const float* W2;  const float* Wr2; const float* a2; const float* Wres2; const float* rel2;
  float* outp;
  float* sA; float* sB; float* sC1; float* sC2;
  ushort_t* b0; ushort_t* b1; ushort_t* Wxb; ushort_t* aggB;
  ushort_t* l1Wb; ushort_t* W1b; ushort_t* R1b; ushort_t* W2b; ushort_t* R2b; ushort_t* l2Wb;
  int* deg; int* rowptr; int* cursor; int* bsums; int* boffs; int* cpk; int* tileCtr;
};

// --------- fused double-GEMM tile: out1 = f1(A[row0..+64] @ W1^T), out2 = f2(out1 @ W2^T)
// W matrices bf16 in original [out][in] layout == MFMA B-operand [n][k] layout.
// M1: 1 = +bias1, leaky(0.01)    2 = elu(acc + aggM bf16, staged via LDS)
// NORM: fused row L2-normalize after f1.  STORE1: write stage-1 bf16 tile to out1.
// M2: 1 = +vec2 bias, leaky(0.01), fp32 out2    3 = bf16 out2 + sA/sB (vec2 = a)
template<int K1, int M1, bool AFP32, bool NORM, bool STORE1, int M2>
__device__ void gtile(int row0, const void* Ap, const ushort_t* Wb1,
                      const float* bias1, const ushort_t* aggM, ushort_t* out1,
                      const ushort_t* Wb2, const float* vec2, void* out2,
                      float* sA, float* sB, char* smem)
{
  constexpr int AP = 40, BP = 40, CP = 136;
  ushort_t* As = (ushort_t*)smem;                  // 64*40*2   = 5120 B
  ushort_t* Bs = As + 64 * AP;                     // 128*40*2  = 10240 B
  ushort_t* Cs = Bs + 128 * BP;                    // 64*136*2  = 17408 B (tot 32768)
  const int tid  = threadIdx.x;
  const int wave = tid >> 6, lane = tid & 63;
  const int l15  = lane & 15, quad = lane >> 4;
  const int M = N;

  if (M1 == 2){                                    // stage agg tile into Cs (coalesced)
    #pragma unroll
    for (int i = 0; i < 4; ++i){
      int idx = tid + 256 * i;
      int r = idx >> 4, c8 = idx & 15;
      int grow = row0 + r;
      uint4 v = make_uint4(0, 0, 0, 0);
      if (grow < M) v = *reinterpret_cast<const uint4*>(aggM + (size_t)grow * 128 + c8 * 8);
      *reinterpret_cast<uint4*>(&Cs[r * CP + c8 * 8]) = v;
    }
  }

  f32x4 acc[8];
  #pragma unroll
  for (int t = 0; t < 8; ++t) acc[t] = (f32x4){0.f, 0.f, 0.f, 0.f};

  // ---------- GEMM 1 ----------
  for (int k0 = 0; k0 < K1; k0 += 32){
    { int r = tid >> 2, q = tid & 3;               // A tile 64x32
      int grow = row0 + r;
      ushort_t v[8] = {0,0,0,0,0,0,0,0};
      if (grow < M){
        if (AFP32){
          const float* ap = (const float*)Ap + (size_t)grow * K1 + k0 + q * 8;
          float4 u0 = *reinterpret_cast<const float4*>(ap);
          float4 u1 = *reinterpret_cast<const float4*>(ap + 4);
          v[0]=f2b(u0.x); v[1]=f2b(u0.y); v[2]=f2b(u0.z); v[3]=f2b(u0.w);
          v[4]=f2b(u1.x); v[5]=f2b(u1.y); v[6]=f2b(u1.z); v[7]=f2b(u1.w);
        } else {
          const uint4 u = *reinterpret_cast<const uint4*>(
              (const ushort_t*)Ap + (size_t)grow * K1 + k0 + q * 8);
          *reinterpret_cast<uint4*>(v) = u;
        }
      }
      *reinterpret_cast<uint4*>(&As[r * AP + q * 8]) = *reinterpret_cast<uint4*>(v);
    }
    { int n = tid >> 1, seg = tid & 1;             // B tile 128x32 from Wb1[n][k]
      const ushort_t* wp = Wb1 + (size_t)n * K1 + k0 + seg * 16;
      uint4 v0 = *reinterpret_cast<const uint4*>(wp);
      uint4 v1 = *reinterpret_cast<const uint4*>(wp + 8);
      *reinterpret_cast<uint4*>(&Bs[n * BP + seg * 16])     = v0;
      *reinterpret_cast<uint4*>(&Bs[n * BP + seg * 16 + 8]) = v1;
    }
    __syncthreads();
    bf16x8 af = *reinterpret_cast<const bf16x8*>(&As[(wave * 16 + l15) * AP + quad * 8]);
    #pragma unroll
    for (int t = 0; t < 8; ++t){
      bf16x8 bfr = *reinterpret_cast<const bf16x8*>(&Bs[(t * 16 + l15) * BP + quad * 8]);
      acc[t] = __builtin_amdgcn_mfma_f32_16x16x32_bf16(af, bfr, acc[t], 0, 0, 0);
    }
    __syncthreads();
  }

  // ---------- epilogue 1 ----------
  float vv[8][4];
  #pragma unroll
  for (int t = 0; t < 8; ++t){
    #pragma unroll
    for (int r = 0; r < 4; ++r){
      int lr  = wave * 16 + quad * 4 + r;
      int col = t * 16 + l15;
      float v = acc[t][r];
      if (M1 == 1){
        v += bias1[col];
        v = v > 0.f ? v : 0.01f * v;
      } else {
        v += b2f_us(Cs[lr * CP + col]);
        v = v > 0.f ? v : __expf(v) - 1.f;
      }
      vv[t][r] = v;
    }
  }
  if (NORM){
    #pragma unroll
    for (int r = 0; r < 4; ++r){
      float ss = 0.f;
      #pragma unroll
      for (int t = 0; t < 8; ++t) ss += vv[t][r] * vv[t][r];
      #pragma unroll
      for (int off = 1; off < 16; off <<= 1) ss += __shfl_xor(ss, off, 64);
      float sc = 1.f / fmaxf(sqrtf(ss), 1e-12f);
      #pragma unroll
      for (int t = 0; t < 8; ++t) vv[t][r] *= sc;
    }
  }
  #pragma unroll
  for (int t = 0; t < 8; ++t){
    #pragma unroll
    for (int r = 0; r < 4; ++r){
      int lr  = wave * 16 + quad * 4 + r;
      int col = t * 16 + l15;
      int grow = row0 + lr;
      ushort_t h = f2b(vv[t][r]);
      if (STORE1 && grow < M) out1[(size_t)grow * 128 + col] = h;
      Cs[lr * CP + col] = h;
    }
  }
  __syncthreads();

  // ---------- GEMM 2: Cs[64x128] @ W2^T ----------
  #pragma unroll
  for (int t = 0; t < 8; ++t) acc[t] = (f32x4){0.f, 0.f, 0.f, 0.f};
  for (int k0 = 0; k0 < 128; k0 += 32){
    { int n = tid >> 1, seg = tid & 1;
      const ushort_t* wp = Wb2 + (size_t)n * 128 + k0 + seg * 16;
      uint4 v0 = *reinterpret_cast<const uint4*>(wp);
      uint4 v1 = *reinterpret_cast<const uint4*>(wp + 8);
      *reinterpret_cast<uint4*>(&Bs[n * BP + seg * 16])     = v0;
      *reinterpret_cast<uint4*>(&Bs[n * BP + seg * 16 + 8]) = v1;
    }
    __syncthreads();
    bf16x8 af = *reinterpret_cast<const bf16x8*>(&Cs[(wave * 16 + l15) * CP + k0 + quad * 8]);
    #pragma unroll
    for (int t = 0; t < 8; ++t){
      bf16x8 bfr = *reinterpret_cast<const bf16x8*>(&Bs[(t * 16 + l15) * BP + quad * 8]);
      acc[t] = __builtin_amdgcn_mfma_f32_16x16x32_bf16(af, bfr, acc[t], 0, 0, 0);
    }
    __syncthreads();
  }

  // ---------- epilogue 2 ----------
  if (M2 == 1){
    #pragma unroll
    for (int t = 0; t < 8; ++t){
      #pragma unroll
      for (int r = 0; r < 4; ++r){
        int grow = row0 + wave * 16 + quad * 4 + r;
        if (grow >= M) continue;
        int col = t * 16 + l15;
        float v = acc[t][r] + vec2[col];
        v = v > 0.f ? v : 0.01f * v;
        ((float*)out2)[(size_t)grow * 128 + col] = v;
      }
    }
  } else {
    #pragma unroll
    for (int t = 0; t < 8; ++t){
      #pragma unroll
      for (int r = 0; r < 4; ++r){
        int grow = row0 + wave * 16 + quad * 4 + r;
        if (grow >= M) continue;
        int col = t * 16 + l15;
        ((ushort_t*)out2)[(size_t)grow * 128 + col] = f2b(acc[t][r]);
      }
    }
    #pragma unroll
    for (int r = 0; r < 4; ++r){
      float pa = 0.f, pb = 0.f;
      #pragma unroll
      for (int t = 0; t < 8; ++t){
        int col = t * 16 + l15;
        pa += acc[t][r] * vec2[col];
        pb += acc[t][r] * vec2[128 + col];
      }
      #pragma unroll
      for (int off = 1; off < 16; off <<= 1){
        pa += __shfl_xor(pa, off, 64);
        pb += __shfl_xor(pb, off, 64);
      }
      int grow = row0 + wave * 16 + quad * 4 + r;
      if (l15 == r && grow < M){ sA[grow] = pa; sB[grow] = pb; }
    }
  }
  __syncthreads();   // smem reusable by caller after this
}

// ------- per-node softmax + aggregate (gridDim-stride waves, 8-wide gather) -------
__device__ void agg_phase(const ushort_t* __restrict__ Wx, const float* __restrict__ sA,
                          const float* __restrict__ sB, const float* __restrict__ sC,
                          const int* __restrict__ rowptr, const int* __restrict__ cpk,
                          uint_t* __restrict__ aggU)
{
  int lane = threadIdx.x & 63;
  int wid  = blockIdx.x * 4 + (threadIdx.x >> 6);
  int wstride = gridDim.x * 4;
  for (int node = wid; node < N; node += wstride){
    int p0 = rowptr[node], p1 = rowptr[node + 1];
    int deg = p1 - p0;
    float sa = sA[node];
    float m = -1e30f, ssum = 0.f, a0 = 0.f, a1 = 0.f;
    for (int c0 = 0; c0 < deg; c0 += 64){
      int cnt = deg - c0; if (cnt > 64) cnt = 64;
      bool ok = lane < cnt;
      int p  = p0 + c0 + (ok ? lane : 0);
      int pk = cpk[p];
      int sn = pk & 0xFFFF;
      float s = sa + sB[sn] + sC[pk >> 16];
      s = s > 0.f ? s : 0.2f * s;                  // leaky_relu(., 0.2)
      float sv = ok ? s : -1e30f;
      #pragma unroll
      for (int off = 32; off > 0; off >>= 1) sv = fmaxf(sv, __shfl_xor(sv, off, 64));
      float mn = fmaxf(m, sv);
      float corr = __expf(m - mn);
      ssum *= corr; a0 *= corr; a1 *= corr;
      float ev = ok ? __expf(s - mn) : 0.f;
      float es = ev;
      #pragma unroll
      for (int off = 32; off > 0; off >>= 1) es += __shfl_xor(es, off, 64);
      ssum += es;
      int png = ok ? pk : 0;
      m = mn;
      for (int e = 0; e < cnt; e += 8){
        #pragma unroll
        for (int j = 0; j < 8; ++j){
          int  nj = __shfl(png, e + j, 64) & 0xFFFF;
          float ej = __shfl(ev,  e + j, 64);
          uint_t u = *reinterpret_cast<const uint_t*>(Wx + (size_t)nj * 128 + lane * 2);
          a0 += ej * b2f_lo(u); a1 += ej * b2f_hi(u);
        }
      }
    }
    float inv = (deg > 0) ? 1.f / ssum : 0.f;      // degree-0 -> zero row
    uint_t o = (uint_t)f2b(a0 * inv) | ((uint_t)f2b(a1 * inv) << 16);
    aggU[(size_t)node * 64 + lane] = o;
  }
}

// ================================ MEGA KERNEL (cooperative) ================================
__global__ __launch_bounds__(256, 2) void mega_k(Par p)
{
  cg::grid_group grid = cg::this_grid();
  __shared__ __align__(16) char smem[32768];
  __shared__ int tS;
  const int b = blockIdx.x, tid = threadIdx.x;
  const int G = gridDim.x;

  // ---------------- P0: weight cvt + deg zero + tileCtr + relsc ----------------
  {
    constexpr int S0 = H * KIN, S1 = H * H, TOT = S0 + 5 * S1;
    for (int i = b * NT + tid; i < TOT; i += G * NT){
      float v;
      if (i < S0) v = p.l1W[i];
      else {
        int j = i - S0, seg = j >> 14, off = j & (S1 - 1);
        const float* srcs[5] = {p.W1, p.Wres1, p.W2, p.Wres2, p.l2W};
        v = srcs[seg][off];
      }
      p.l1Wb[i] = f2b(v);
    }
    for (int i = b * NT + tid; i < N; i += G * NT) p.deg[i] = 0;
    if (b == 0 && tid == 0) *p.tileCtr = 0;
    if (b >= G - 2){                               // relsc on the last two blocks
      int L = b - (G - 2);
      const float* rel = L ? p.rel2 : p.rel1;
      const float* Wr  = L ? p.Wr2  : p.Wr1;
      const float* a   = L ? p.a2   : p.a1;
      float*       sC  = L ? p.sC2  : p.sC1;
      float* red = (float*)smem;
      int nn = tid >> 1, half = tid & 1;
      float aC = a[256 + nn];
      for (int r = 0; r < NR; ++r){
        float acc = 0.f;
        for (int k = half * 100; k < half * 100 + 100; ++k)
          acc += rel[r * RD + k] * Wr[nn * RD + k];
        red[tid] = acc * aC;
        __syncthreads();
        for (int s = 128; s > 0; s >>= 1){
          if (tid < s) red[tid] += red[tid + s];
          __syncthreads();
        }
        if (tid == 0) sC[r] = red[0];
        __syncthreads();
      }
    }
  }
  __threadfence(); grid.sync();

  // ------- P1: degcount (blocks < NSCAN), then EVERYONE drains the G1 tile queue -------
  if (b < NSCAN){
    for (int e = b * NT + tid; e < E; e += NSCAN * NT) atomicAdd(&p.deg[p.edst[e]], 1);
  }
  while (true){
    if (tid == 0) tS = atomicAdd(p.tileCtr, 1);
    __syncthreads();
    int t = tS;
    if (t >= GTILES) break;
    gtile<KIN, 1, true, false, true, 3>(t * 64, p.x, p.l1Wb, p.l1b, nullptr, p.b0,
                                        p.W1b, p.a1, p.Wxb, p.sA, p.sB, smem);
  }
  __threadfence(); grid.sync();

  // ------- P2: per-chunk exclusive scan (blocks < NSCAN) -------
  if (b < NSCAN){
    int* s = (int*)smem;
    int i = b * 256 + tid;
    int v = (i < N) ? p.deg[i] : 0;
    s[tid] = v; __syncthreads();
    for (int off = 1; off < 256; off <<= 1){
      int t2 = (tid >= off) ? s[tid - off] : 0;
      __syncthreads();
      s[tid] += t2;
      __syncthreads();
    }
    if (i < N) p.rowptr[i] = s[tid] - v;           // chunk-exclusive
    if (tid == 255) p.bsums[b] = s[255];
  }
  __threadfence(); grid.sync();

  // ------- P3: each scan block scans ALL bsums, finalizes its rowptr/cursor chunk -------
  if (b < NSCAN){
    int* s = (int*)smem;
    int v = (tid < NSCAN) ? p.bsums[tid] : 0;
    s[tid] = v; __syncthreads();
    for (int off = 1; off < 256; off <<= 1){
      int t2 = (tid >= off) ? s[tid - off] : 0;
      __syncthreads();
      s[tid] += t2;
      __syncthreads();
    }
    int boff = (b == 0) ? 0 : s[b - 1];
    int i = b * 256 + tid;
    if (i < N){
      int r = p.rowptr[i] + boff;
      p.rowptr[i] = r; p.cursor[i] = r;
    }
    if (b == 0 && tid == 0) p.rowptr[N] = E;
  }
  __threadfence(); grid.sync();

  // ---------------- P4: fill CSR (all blocks), (type<<16)|src packed ----------------
  for (int e = b * NT + tid; e < E; e += G * NT){
    int d = p.edst[e];
    int pos = atomicAdd(&p.cursor[d], 1);
    p.cpk[pos] = p.esrc[e] | (p.et[e] << 16);
  }
  __threadfence(); grid.sync();

  // ---------------- P5: agg layer 1 ----------------
  agg_phase(p.Wxb, p.sA, p.sB, p.sC1, p.rowptr, p.cpk, (uint_t*)p.aggB);
  __threadfence(); grid.sync();

  // ------- P6: G2 = [h1 = elu(agg1 + b0@R1^T)] -> b1; Wx2 = h1@W2^T (+sA/sB) -------
  for (int t = b; t < GTILES; t += G)
    gtile<H, 2, false, false, true, 3>(t * 64, p.b0, p.R1b, nullptr, p.aggB, p.b1,
                                       p.W2b, p.a2, p.Wxb, p.sA, p.sB, smem);
  __threadfence(); grid.sync();

  // ---------------- P7: agg layer 2 ----------------
  agg_phase(p.Wxb, p.sA, p.sB, p.sC2, p.rowptr, p.cpk, (uint_t*)p.aggB);
  __threadfence(); grid.sync();

  // ------- P8: G3 = normalize(elu(agg2 + b1@R2^T)); out = leaky(h2@l2W^T + b) -------
  for (int t = b; t < GTILES; t += G)
    gtile<H, 2, false, true, false, 1>(t * 64, p.b1, p.R2b, nullptr, p.aggB, nullptr,
                                       p.l2Wb, p.l2b, p.outp, nullptr, nullptr, smem);
}

// ================== fallback kernels (round-4 proven path) ==================
__global__ void prep_k(Par p){
  constexpr int S0 = H * KIN, S1 = H * H;
  int b = blockIdx.x, tid = threadIdx.x;
  if (b < 704){
    int i = b * 256 + tid;
    float v;
    if (i < S0) v = p.l1W[i];
    else {
      int j = i - S0, seg = j >> 14, off = j & (S1 - 1);
      const float* srcs[5] = {p.W1, p.Wres1, p.W2, p.Wres2, p.l2W};
      v = srcs[seg][off];
    }
    p.l1Wb[i] = f2b(v);
  } else if (b < 900){
    int i = (b - 704) * 256 + tid;
    if (i < N) p.deg[i] = 0;
  } else {
    int L = b - 900;
    const float* rel = L ? p.rel2 : p.rel1;
    const float* Wr  = L ? p.Wr2  : p.Wr1;
    const float* a   = L ? p.a2   : p.a1;
    float*       sC  = L ? p.sC2  : p.sC1;
    __shared__ float red[256];
    int nn = tid >> 1, half = tid & 1;
    float aC = a[256 + nn];
    for (int r = 0; r < NR; ++r){
      float acc = 0.f;
      for (int k = half * 100; k < half * 100 + 100; ++k)
        acc += rel[r * RD + k] * Wr[nn * RD + k];
      red[tid] = acc * aC;
      __syncthreads();
      for (int s = 128; s > 0; s >>= 1){
        if (tid < s) red[tid] += red[tid + s];
        __syncthreads();
      }
      if (tid == 0) sC[r] = red[0];
      __syncthreads();
    }
  }
}

__global__ void degcount_k(const int* __restrict__ dst, int* __restrict__ deg){
  int e = blockIdx.x * 256 + threadIdx.x;
  if (e < E) atomicAdd(&deg[dst[e]], 1);
}

__global__ void scan1_k(const int* __restrict__ deg, int* __restrict__ chunk,
                        int* __restrict__ bsums, int n){
  __shared__ int s[256];
  int tid = threadIdx.x, i = blockIdx.x * 256 + tid;
  int v = (i < n) ? deg[i] : 0;
  s[tid] = v; __syncthreads();
  for (int off = 1; off < 256; off <<= 1){
    int t = (tid >= off) ? s[tid - off] : 0;
    __syncthreads();
    s[tid] += t;
    __syncthreads();
  }
  if (i < n) chunk[i] = s[tid] - v;
  if (tid == 255) bsums[blockIdx.x] = s[255];
}

__global__ void scan2_k(const int* __restrict__ bsums, int* __restrict__ boffs, int nb){
  __shared__ int s[256];
  int tid = threadIdx.x;
  int v = (tid < nb) ? bsums[tid] : 0;
  s[tid] = v; __syncthreads();
  for (int off = 1; off < 256; off <<= 1){
    int t = (tid >= off) ? s[tid - off] : 0;
    __syncthreads();
    s[tid] += t;
    __syncthreads();
  }
  if (tid < nb) boffs[tid] = s[tid] - v;
}

__global__ void scan3_k(int* __restrict__ rowptr, const int* __restrict__ boffs,
                        int* __restrict__ cursor, int n, int total){
  int i = blockIdx.x * 256 + threadIdx.x;
  if (i < n){
    int v = rowptr[i] + boffs[blockIdx.x];
    rowptr[i] = v; cursor[i] = v;
  }
  if (i == 0) rowptr[n] = total;
}

__global__ void fill_k(const int* __restrict__ src, const int* __restrict__ dst,
                       const int* __restrict__ et, int* __restrict__ cursor,
                       int* __restrict__ cpk){
  int e = blockIdx.x * 256 + threadIdx.x;
  if (e < E){
    int d = dst[e];
    int pp = atomicAdd(&cursor[d], 1);
    cpk[pp] = src[e] | (et[e] << 16);
  }
}

template<int K1, int M1, bool AFP32, bool NORM, bool STORE1, int M2>
__global__ __launch_bounds__(256) void gfused_k(
    const void* Ap, const ushort_t* Wb1, const float* bias1, const ushort_t* aggM,
    ushort_t* out1, const ushort_t* Wb2, const float* vec2, void* out2,
    float* sA, float* sB){
  __shared__ __align__(16) char smem[32768];
  gtile<K1, M1, AFP32, NORM, STORE1, M2>(blockIdx.x * 64, Ap, Wb1, bias1, aggM, out1,
                                         Wb2, vec2, out2, sA, sB, smem);
}

__global__ void agg_k(const ushort_t* Wx, const float* sA, const float* sB,
                      const float* sC, const int* rowptr, const int* cpk, uint_t* aggU){
  agg_phase(Wx, sA, sB, sC, rowptr, cpk, aggU);
}

} // namespace

extern "C" void kernel_launch(void* const* d_in, const int* in_sizes, int n_in,
                              void* d_out, int out_size, void* d_ws, size_t ws_size,
                              hipStream_t stream)
{
  Par p;
  p.x     = (const float*)d_in[0];
  const int* eidx = (const int*)d_in[1];
  p.esrc  = eidx;
  p.edst  = eidx + E;
  p.et    = (const int*)d_in[2];
  p.l1W   = (const float*)d_in[3];
  p.l1b   = (const float*)d_in[4];
  p.l2W   = (const float*)d_in[5];
  p.l2b   = (const float*)d_in[6];
  p.W1    = (const float*)d_in[7];
  p.Wr1   = (const float*)d_in[8];
  p.a1    = (const float*)d_in[9];
  p.Wres1 = (const float*)d_in[10];
  p.rel1  = (const float*)d_in[11];
  p.W2    = (const float*)d_in[12];
  p.Wr2   = (const float*)d_in[13];
  p.a2    = (const float*)d_in[14];
  p.Wres2 = (const float*)d_in[15];
  p.rel2  = (const float*)d_in[16];
  p.outp  = (float*)d_out;

  // -------- workspace layout --------
  float* f = (float*)d_ws;
  size_t o = 0;
  p.sA  = f + o; o += N;
  p.sB  = f + o; o += N;
  p.sC1 = f + o; o += 8;
  p.sC2 = f + o; o += 8;
  ushort_t* us = (ushort_t*)(f + o);
  size_t ou = 0;
  p.b0   = us + ou; ou += (size_t)N * H;
  p.b1   = us + ou; ou += (size_t)N * H;
  p.Wxb  = us + ou; ou += (size_t)N * H;
  p.aggB = us + ou; ou += (size_t)N * H;
  p.l1Wb = us + ou; ou += (size_t)H * KIN + 5 * H * H;
  p.W1b  = p.l1Wb + H * KIN;
  p.R1b  = p.W1b + H * H;
  p.W2b  = p.R1b + H * H;
  p.R2b  = p.W2b + H * H;
  p.l2Wb = p.R2b + H * H;
  ou = (ou + 1) & ~(size_t)1;                       // 4B-align int region
  int* wi = (int*)(us + ou);
  size_t oi = 0;
  p.deg     = wi + oi; oi += N;
  p.rowptr  = wi + oi; oi += N + 1;
  p.cursor  = wi + oi; oi += N;
  p.bsums   = wi + oi; oi += 256;
  p.boffs   = wi + oi; oi += 256;
  p.cpk     = wi + oi; oi += E;
  p.tileCtr = wi + oi; oi += 4;

  // -------- try the cooperative mega-kernel with an occupancy-sized grid --------
  hipError_t err = hipErrorUnknown;
  int dev = 0;
  (void)hipGetDevice(&dev);
  int numCU = 0, maxB = 0;
  (void)hipDeviceGetAttribute(&numCU, hipDeviceAttributeMultiprocessorCount, dev);
  hipError_t oe = hipOccupancyMaxActiveBlocksPerMultiprocessor(&maxB, mega_k, NT, 0);
  int grid = (oe == hipSuccess && numCU > 0 && maxB > 0) ? maxB * numCU : 0;
  if (grid > 768) grid = 768;
  if (grid >= 208){                                 // need >= NSCAN blocks for the scan
    void* args[] = { &p };
    err = hipLaunchCooperativeKernel((const void*)mega_k, dim3(grid), dim3(NT), args, 0, stream);
  }

  // -------- deterministic fallback: proven round-4 multi-dispatch path --------
  if (err != hipSuccess){
    const int EB    = (E + 255) / 256;
    const int NB256 = (N + 255) / 256;
    const int GB    = GTILES;
    const int NB4   = (N + 3) / 4;
    prep_k<<<902, 256, 0, stream>>>(p);
    degcount_k<<<EB, 256, 0, stream>>>(p.edst, p.deg);
    scan1_k<<<NB256, 256, 0, stream>>>(p.deg, p.rowptr, p.bsums, N);
    scan2_k<<<1, 256, 0, stream>>>(p.bsums, p.boffs, NB256);
    scan3_k<<<NB256, 256, 0, stream>>>(p.rowptr, p.boffs, p.cursor, N, E);
    fill_k<<<EB, 256, 0, stream>>>(p.esrc, p.edst, p.et, p.cursor, p.cpk);

    gfused_k<KIN, 1, true, false, true, 3><<<GB, 256, 0, stream>>>(
        p.x, p.l1Wb, p.l1b, nullptr, p.b0, p.W1b, p.a1, p.Wxb, p.sA, p.sB);
    agg_k<<<NB4, 256, 0, stream>>>(p.Wxb, p.sA, p.sB, p.sC1, p.rowptr, p.cpk, (uint_t*)p.aggB);

    gfused_k<H, 2, false, false, true, 3><<<GB, 256, 0, stream>>>(
        p.b0, p.R1b, nullptr, p.aggB, p.b1, p.W2b, p.a2, p.Wxb, p.sA, p.sB);
    agg_k<<<NB4, 256, 0, stream>>>(p.Wxb, p.sA, p.sB, p.sC2, p.rowptr, p.cpk, (uint_t*)p.aggB);

    gfused_k<H, 2, false, true, false, 1><<<GB, 256, 0, stream>>>(
        p.b1, p.R2b, nullptr, p.aggB, nullptr, p.l2Wb, p.l2b, p.outp, nullptr, nullptr);
  }
}